// Round 13
// baseline (73.730 us; speedup 1.0000x reference)
//
#include <hip/hip_runtime.h>
#include <stdint.h>

#define B_ 2
#define L_ 2048
#define D_ 512
#define H_ 8
#define DH_ 64

using frag8 = __attribute__((ext_vector_type(8))) short;   // 8 bf16 in 4 VGPRs
using bf4   = __attribute__((ext_vector_type(4))) short;   // 4 bf16 (one b64)
using f32x4 = __attribute__((ext_vector_type(4))) float;   // MFMA accumulator
using u32x4 = __attribute__((ext_vector_type(4))) unsigned int;

#define QSC 0.18033688011112042f   /* 0.125 * log2(e): exp2-domain scale folded into Q */

__device__ __forceinline__ unsigned short f2bf(float f) {
    unsigned int u = __float_as_uint(f);
    u += 0x7fffu + ((u >> 16) & 1u);      // RNE
    return (unsigned short)(u >> 16);
}

__device__ __forceinline__ unsigned int cvtpk(float lo, float hi_) {
    unsigned int r;
    asm("v_cvt_pk_bf16_f32 %0, %1, %2" : "=v"(r) : "v"(lo), "v"(hi_));
    return r;
}

__device__ __forceinline__ frag8 pk8(f32x4 lo, f32x4 hh) {
    union { u32x4 u; frag8 f; } v;
    v.u = (u32x4){cvtpk(lo[0], lo[1]), cvtpk(lo[2], lo[3]),
                  cvtpk(hh[0], hh[1]), cvtpk(hh[2], hh[3])};
    return v.f;
}

__device__ __forceinline__ void gl2lds16(const void* g, void* lds) {
    __builtin_amdgcn_global_load_lds((const __attribute__((address_space(1))) void*)g,
                                     (__attribute__((address_space(3))) void*)lds,
                                     16, 0, 0);
}

template<int N>
__device__ __forceinline__ void vmwait() {
    asm volatile("s_waitcnt vmcnt(%0)" :: "n"(N) : "memory");
}

// ---------------- prep: weight fp32 -> bf16 + energy mask ----------------
__global__ __launch_bounds__(256) void cvt_mask_kernel(
    const float* __restrict__ Wq, const float* __restrict__ Wk, const float* __restrict__ Wv,
    const float* __restrict__ Wo, const float* __restrict__ ec,
    unsigned short* wqb, unsigned short* wkb, unsigned short* wvb, unsigned short* wob,
    float* __restrict__ mk)
{
    const long NW = (long)D_ * D_;            // 262144
    long q4 = (long)blockIdx.x * 256 + threadIdx.x;
    if (q4 < NW) {                             // 4 matrices, 4 elems/thread
        long i = q4 * 4;
        int w = (int)(i / NW);
        long off = i - (long)w * NW;
        const float* src = (w == 0) ? Wq : (w == 1) ? Wk : (w == 2) ? Wv : Wo;
        unsigned short* dst = (w == 0) ? wqb : (w == 1) ? wkb : (w == 2) ? wvb : wob;
        float4 v = *(const float4*)(src + off);
        ushort4 o;
        o.x = f2bf(v.x); o.y = f2bf(v.y); o.z = f2bf(v.z); o.w = f2bf(v.w);
        *(ushort4*)(dst + off) = o;
    } else {
        long i = q4 - NW;                      // 0..B*L-1
        if (i < B_ * L_) {
            const float4* p4 = (const float4*)(ec + i * 16);
            float s = 0.0f;
#pragma unroll
            for (int j = 0; j < 4; ++j) {
                float4 v = p4[j];
                s += fabsf(v.x) + fabsf(v.y) + fabsf(v.z) + fabsf(v.w);
            }
            float energy = s * (1.0f / 16.0f);
            mk[i] = (energy > 0.1f) ? 0.0f : -1.0e9f;
        }
    }
}

// ---------------- GEMM: C[M,N] = A[M,K] * W[N,K]^T + bias ----------------
// Double-buffered LDS, counted-vmcnt pipeline, raw barriers, XCD-chunked swizzle,
// bias as MFMA C-init. AF32=1: A staged as f32 via global_load_lds, converted
// to bf16 at fragment-read time (v_cvt_pk_bf16_f32).
// mode 0: bf16 store; 1: bf16 * QSC (Q proj); 2: bf16 transposed V^T store with
// R5 slot swizzle (conflict-free b64 PV); 3: f32 store (out proj).
struct GemmArgs { const void* A; const unsigned short* W;
                  const float* bias; void* C; int mode; };

template<int BM, int BN, int AF32>
__global__ __launch_bounds__(256) void gemm_kernel(GemmArgs a0, GemmArgs a1, GemmArgs a2,
                                                   int M, int N, int K)
{
    // XCD-chunked swizzle (grid size divisible by 8 by construction)
    const int nwg = gridDim.x * gridDim.y * gridDim.z;
    int flat = blockIdx.x + gridDim.x * (blockIdx.y + gridDim.y * blockIdx.z);
    int swz  = (flat & 7) * (nwg >> 3) + (flat >> 3);
    const int bx = swz % gridDim.x;
    int t2 = swz / gridDim.x;
    const int by = t2 % gridDim.y;
    const int bz = t2 / gridDim.y;

    GemmArgs ga = bz == 0 ? a0 : (bz == 1 ? a1 : a2);
    const float* __restrict__ Af = (const float*)ga.A;
    const unsigned short* __restrict__ Ab = (const unsigned short*)ga.A;
    const unsigned short* __restrict__ W = ga.W;
    const float* __restrict__ bias = ga.bias;

    constexpr int MF = BM / 32;
    constexpr int NF = BN / 32;
    constexpr int NL = (AF32 ? BM / 16 : BM / 32) + BN / 32;

    __shared__ __align__(16) char sA[(size_t)2 * BM * 64 * (AF32 ? 4 : 2)];
    __shared__ __align__(16) unsigned short Bs[2][BN * 64];
    float* AsF = (float*)sA;
    unsigned short* As16 = (unsigned short*)sA;

    const int tid  = threadIdx.x;
    const int lane = tid & 63;
    const int wave = tid >> 6;
    const int hi   = lane >> 4;
    const int ln   = lane & 15;
    const int wr   = wave >> 1;
    const int wc   = wave & 1;

    const long mBase = (long)by * BM;
    const long nBase = (long)bx * BN;

    // bias as C-init (per output column)
    f32x4 acc[MF][NF];
#pragma unroll
    for (int n = 0; n < NF; ++n) {
        float bv = bias[nBase + wc * (BN / 2) + n * 16 + ln];
#pragma unroll
        for (int m = 0; m < MF; ++m) acc[m][n] = (f32x4){bv, bv, bv, bv};
    }

#define GSTAGE(KT, BUF) do {                                                    \
    if (AF32) {                                                                 \
        _Pragma("unroll")                                                       \
        for (int i_ = 0; i_ < BM / 16; ++i_) {       /* 16B chunks of f32 */    \
            int cl_ = i_ * 256 + tid;                                           \
            int r_ = cl_ >> 4, c_ = cl_ & 15, s_ = c_ ^ (r_ & 15);              \
            gl2lds16(Af + (mBase + r_) * K + (KT) + s_ * 4,                     \
                     AsF + ((BUF) * BM + r_) * 64 + (cl_ & 15) * 4);            \
        }                                                                       \
    } else {                                                                    \
        _Pragma("unroll")                                                       \
        for (int i_ = 0; i_ < BM / 32; ++i_) {                                  \
            int cl_ = i_ * 256 + tid;                                           \
            int r_ = cl_ >> 3, c_ = cl_ & 7, s_ = c_ ^ (r_ & 7);                \
            gl2lds16(Ab + (mBase + r_) * K + (KT) + s_ * 8,                     \
                     As16 + ((BUF) * BM + r_) * 64 + (cl_ & 7) * 8);            \
        }                                                                       \
    }                                                                           \
    _Pragma("unroll")                                                           \
    for (int i_ = 0; i_ < BN / 32; ++i_) {                                      \
        int cl_ = i_ * 256 + tid;                                               \
        int r_ = cl_ >> 3, c_ = cl_ & 7, s_ = c_ ^ (r_ & 7);                    \
        gl2lds16(W + (nBase + r_) * K + (KT) + s_ * 8, Bs[BUF] + cl_ * 8);      \
    }                                                                           \
} while (0)

    GSTAGE(0, 0);

    const int nk = K / 64;
    for (int t = 0; t < nk; ++t) {
        const int buf = t & 1;
        if (t + 1 < nk) {
            GSTAGE((t + 1) * 64, buf ^ 1);   // prefetch stays in flight across barriers
            vmwait<NL>();                     // wait only for tile t's loads
        } else {
            vmwait<0>();
        }
        __builtin_amdgcn_s_barrier();
        __builtin_amdgcn_sched_barrier(0);

        frag8 af[2][MF], bfr[2][NF];
#pragma unroll
        for (int kk = 0; kk < 2; ++kk) {
#pragma unroll
            for (int m = 0; m < MF; ++m) {
                int row = wr * (BM / 2) + m * 16 + ln;
                if (AF32) {
                    int c0 = kk * 8 + hi * 2;
                    int p0 = c0 ^ (row & 15);
                    int p1 = (c0 + 1) ^ (row & 15);
                    f32x4 lo = *(const f32x4*)(AsF + ((long)buf * BM + row) * 64 + p0 * 4);
                    f32x4 hh = *(const f32x4*)(AsF + ((long)buf * BM + row) * 64 + p1 * 4);
                    af[kk][m] = pk8(lo, hh);
                } else {
                    int c = (kk * 4 + hi) ^ (row & 7);
                    af[kk][m] = *(const frag8*)(As16 + ((long)buf * BM + row) * 64 + c * 8);
                }
            }
#pragma unroll
            for (int n = 0; n < NF; ++n) {
                int row = wc * (BN / 2) + n * 16 + ln;
                int c = (kk * 4 + hi) ^ (row & 7);
                bfr[kk][n] = *(const frag8*)(Bs[buf] + row * 64 + c * 8);
            }
        }
        __builtin_amdgcn_s_setprio(1);
#pragma unroll
        for (int kk = 0; kk < 2; ++kk)
#pragma unroll
            for (int m = 0; m < MF; ++m)
#pragma unroll
                for (int n = 0; n < NF; ++n)
                    acc[m][n] = __builtin_amdgcn_mfma_f32_16x16x32_bf16(af[kk][m], bfr[kk][n], acc[m][n], 0, 0, 0);
        __builtin_amdgcn_s_setprio(0);
        __builtin_amdgcn_sched_barrier(0);
        __builtin_amdgcn_s_barrier();        // raw: prefetch stays in flight
    }
#undef GSTAGE

    const int mode = ga.mode;
#pragma unroll
    for (int m = 0; m < MF; ++m) {
#pragma unroll
        for (int n = 0; n < NF; ++n) {
            long col = nBase + wc * (BN / 2) + n * 16 + ln;
#pragma unroll
            for (int j = 0; j < 4; ++j) {
                long row = mBase + wr * (BM / 2) + m * 16 + hi * 4 + j;
                float v = acc[m][n][j];
                if (mode == 3) {
                    ((float*)ga.C)[row * N + col] = v;
                } else if (mode == 2) {
                    // V^T store: R5 slot swizzle (key-group s at s^sw within 64)
                    int dh = (int)col & 63;
                    int swv = ((dh & 7) << 1) | ((dh >> 3) & 1);
                    long nt = (row & ~63L) | (long)(((((int)(row >> 2)) & 15) ^ swv) << 2) | (row & 3);
                    ((unsigned short*)ga.C)[col * (long)(B_ * L_) + nt] = f2bf(v);
                } else {
                    if (mode == 1) v *= QSC;
                    ((unsigned short*)ga.C)[row * N + col] = f2bf(v);
                }
            }
        }
    }
}

// ---------------- fused flash attention ----------------
// grid (L/64, B*H) with XCD-chunked remap. 512 thr = 8 waves; groups 0/1 =
// even/odd 64-key tiles, double-buffered K/V, DEFERRED softmax/PV, ONE barrier
// per iter. All global pointers strength-reduced (incremental); LDS buffers
// via ^8192 offset toggle; per-lane l accumulated, cross-lane reduced ONCE at
// end. Mask = MFMA C-init (registers, prefetched a tile ahead). exp2-domain
// softmax, defer-max THR=8. V^T slot-swizzled in global: conflict-free b64 PV.
__global__ __launch_bounds__(512, 4) void attn_kernel(
    const unsigned short* __restrict__ Qg, const unsigned short* __restrict__ Kg,
    const unsigned short* __restrict__ Vt, const float* __restrict__ mkg,
    unsigned short* __restrict__ Og)
{
    const int tid  = threadIdx.x;
    const int lane = tid & 63;
    const int wave = tid >> 6;
    const int grp  = wave >> 2;
    const int wq   = wave & 3;
    const int gtid = tid & 255;
    const int hi   = lane >> 4;
    const int ln   = lane & 15;

    // XCD-chunked remap: XCD x owns heads {2x, 2x+1}
    const int flat = blockIdx.x + gridDim.x * blockIdx.y;
    const int nwg  = gridDim.x * gridDim.y;
    const int s    = (flat & 7) * (nwg >> 3) + (flat >> 3);
    const int qt   = s & (gridDim.x - 1);
    const int bh   = s / gridDim.x;

    const int b  = bh >> 3, h = bh & 7;
    const unsigned short* Qb = Qg + ((long)b * L_) * D_ + h * DH_;
    const unsigned short* Kb = Kg + ((long)b * L_) * D_ + h * DH_;
    const unsigned short* Vb = Vt + (long)(h * DH_) * (B_ * L_) + (long)b * L_;
    const float* mkb = mkg + (long)b * L_;

    __shared__ __align__(16) char smem[65536];
    unsigned short* KsG = (unsigned short*)(smem + grp * 32768);
    unsigned short* VsG = (unsigned short*)(smem + grp * 32768 + 16384);

    const int q0 = qt * 64 + wq * 16;

    frag8 qf[2];
#pragma unroll
    for (int ks = 0; ks < 2; ++ks)
        qf[ks] = *(const frag8*)(Qb + (long)(q0 + ln) * D_ + ks * 32 + hi * 8);

    // ---- incremental global stage pointers (advance 2 tiles / iter) ----
    const int r0 = gtid >> 3, c0 = gtid & 7;
    const unsigned short* kg0 = Kb + (long)(grp * 64 + r0) * D_ + ((c0 ^ (r0 & 7)) << 3);
    const unsigned short* kg1 = kg0 + 32 * D_;
    const unsigned short* vg0 = Vb + (long)r0 * (B_ * L_) + grp * 64 + (c0 << 3);
    const unsigned short* vg1 = vg0 + (long)32 * (B_ * L_);
    const float* mp = mkb + grp * 64 + 4 * hi;

    // LDS staging destinations (toggle ^8192 bytes after each STAGE)
    unsigned short* kd0 = KsG + gtid * 8;
    unsigned short* kd1 = KsG + 2048 + gtid * 8;
    unsigned short* vd0 = VsG + gtid * 8;
    unsigned short* vd1 = VsG + 2048 + gtid * 8;

    // lane-fixed LDS read bases + buffer byte-offset toggles
    const int sw = ((ln & 7) << 1) | ((ln >> 3) & 1);
    const char* krp0 = (const char*)KsG + ln * 128 + ((hi ^ (ln & 7)) << 4);
    const char* krp1 = (const char*)KsG + ln * 128 + (((4 + hi) ^ (ln & 7)) << 4);
    const char* vrp0 = (const char*)VsG + ln * 128 + (((hi     ) ^ sw) << 3);
    const char* vrp1 = (const char*)VsG + ln * 128 + (((hi + 4 ) ^ sw) << 3);
    const char* vrp2 = (const char*)VsG + ln * 128 + (((hi + 8 ) ^ sw) << 3);
    const char* vrp3 = (const char*)VsG + ln * 128 + (((hi + 12) ^ sw) << 3);
    int kbo = 0, vbo = 0;

#define STAGE2() do {                                                           \
    gl2lds16(kg0, kd0); gl2lds16(vg0, vd0);                                     \
    gl2lds16(kg1, kd1); gl2lds16(vg1, vd1);                                     \
    kg0 += 128 * D_; kg1 += 128 * D_; vg0 += 128; vg1 += 128;                   \
    kd0 = (unsigned short*)((uintptr_t)kd0 ^ 8192);                             \
    kd1 = (unsigned short*)((uintptr_t)kd1 ^ 8192);                             \
    vd0 = (unsigned short*)((uintptr_t)vd0 ^ 8192);                             \
    vd1 = (unsigned short*)((uintptr_t)vd1 ^ 8192);                             \
} while (0)

    f32x4 o[4];
#pragma unroll
    for (int g = 0; g < 4; ++g) o[g] = (f32x4){0.f, 0.f, 0.f, 0.f};
    float m_run = -__builtin_inff();
    float l_run = 0.0f;            // per-lane partial; reduced once at end
    f32x4 scp[4];                  // deferred masked scores (previous tile)
    f32x4 mA0, mA1, mA2, mA3;      // mask regs (C-init source)

#define LOADM() do {                                                            \
    mA0 = *(const f32x4*)(mp);                                                  \
    mA1 = *(const f32x4*)(mp + 16);                                             \
    mA2 = *(const f32x4*)(mp + 32);                                             \
    mA3 = *(const f32x4*)(mp + 48);                                             \
    mp += 128;                                                                  \
} while (0)

    // deferred softmax + PV on scp (per-lane l, no cross-lane l reduce)
    auto SOFTPV = [&]() {
        float a0 = fmaxf(fmaxf(scp[0][0], scp[0][1]), fmaxf(scp[0][2], scp[0][3]));
        float a1 = fmaxf(fmaxf(scp[1][0], scp[1][1]), fmaxf(scp[1][2], scp[1][3]));
        float a2 = fmaxf(fmaxf(scp[2][0], scp[2][1]), fmaxf(scp[2][2], scp[2][3]));
        float a3 = fmaxf(fmaxf(scp[3][0], scp[3][1]), fmaxf(scp[3][2], scp[3][3]));
        float tl = fmaxf(fmaxf(a0, a1), fmaxf(a2, a3));
        float tA = __shfl_xor(tl, 16);
        float tB = __shfl_xor(tl, 32);
        float tC = __shfl_xor(tl, 48);
        float tmax = fmaxf(fmaxf(tl, tA), fmaxf(tB, tC));

        if (!__all(tmax <= m_run + 8.0f)) {
            float m_new = fmaxf(m_run, tmax);
            float alpha = __builtin_amdgcn_exp2f(m_run - m_new);
            float b0 = __shfl(alpha, 4 * hi + 0);
            float b1 = __shfl(alpha, 4 * hi + 1);
            float b2 = __shfl(alpha, 4 * hi + 2);
            float b3 = __shfl(alpha, 4 * hi + 3);
#pragma unroll
            for (int g = 0; g < 4; ++g) {
                o[g][0] *= b0; o[g][1] *= b1; o[g][2] *= b2; o[g][3] *= b3;
            }
            l_run *= alpha;
            m_run = m_new;
        }

        float p[16];
#pragma unroll
        for (int sh = 0; sh < 4; ++sh)
#pragma unroll
            for (int r = 0; r < 4; ++r)
                p[sh * 4 + r] = __builtin_amdgcn_exp2f(scp[sh][r] - m_run);
        float s01 = (p[0] + p[1]) + (p[2] + p[3]);
        float s23 = (p[4] + p[5]) + (p[6] + p[7]);
        float s45 = (p[8] + p[9]) + (p[10] + p[11]);
        float s67 = (p[12] + p[13]) + (p[14] + p[15]);
        l_run += (s01 + s23) + (s45 + s67);

        union PU { u32x4 u; frag8 f; } p0u, p1u;
        p0u.u = (u32x4){cvtpk(p[0], p[1]),  cvtpk(p[2], p[3]),
                        cvtpk(p[4], p[5]),  cvtpk(p[6], p[7])};
        p1u.u = (u32x4){cvtpk(p[8], p[9]),  cvtpk(p[10], p[11]),
                        cvtpk(p[12], p[13]), cvtpk(p[14], p[15])};

        __builtin_amdgcn_s_setprio(1);
#pragma unroll
        for (int g = 0; g < 4; ++g) {
            bf4 v0 = *(const bf4*)(vrp0 + vbo + g * 2048);
            bf4 v1 = *(const bf4*)(vrp1 + vbo + g * 2048);
            bf4 v2 = *(const bf4*)(vrp2 + vbo + g * 2048);
            bf4 v3 = *(const bf4*)(vrp3 + vbo + g * 2048);
            frag8 vf0 = __builtin_shufflevector(v0, v1, 0, 1, 2, 3, 4, 5, 6, 7);
            frag8 vf1 = __builtin_shufflevector(v2, v3, 0, 1, 2, 3, 4, 5, 6, 7);
            o[g] = __builtin_amdgcn_mfma_f32_16x16x32_bf16(p0u.f, vf0, o[g], 0, 0, 0);
            o[g] = __builtin_amdgcn_mfma_f32_16x16x32_bf16(p1u.f, vf1, o[g], 0, 0, 0);
        }
        __builtin_amdgcn_s_setprio(0);
        vbo ^= 8192;
    };

    // QK^T of current K buffer; mask regs enter as MFMA C-init; result -> scp
    auto QKSAVE = [&]() {
        scp[0] = mA0; scp[1] = mA1; scp[2] = mA2; scp[3] = mA3;
        __builtin_amdgcn_s_setprio(1);
#pragma unroll
        for (int sh = 0; sh < 4; ++sh) {
            frag8 k0 = *(const frag8*)(krp0 + kbo + sh * 2048);
            frag8 k1 = *(const frag8*)(krp1 + kbo + sh * 2048);
            scp[sh] = __builtin_amdgcn_mfma_f32_16x16x32_bf16(k0, qf[0], scp[sh], 0, 0, 0);
            scp[sh] = __builtin_amdgcn_mfma_f32_16x16x32_bf16(k1, qf[1], scp[sh], 0, 0, 0);
        }
        __builtin_amdgcn_s_setprio(0);
        kbo ^= 8192;
    };

    // ---- iteration 0 (peeled) ----
    STAGE2();                      // tile 0 -> buf 0
    LOADM();                       // mask tile 0 -> mA
    vmwait<0>();
    __builtin_amdgcn_s_barrier();
    __builtin_amdgcn_sched_barrier(0);
    STAGE2();                      // tile 1 -> buf 1
    QKSAVE();                      // tile 0 (consumes mA)
    LOADM();                       // mask tile 1 -> mA

    // ---- steady state ----
    for (int i = 1; i < 16; ++i) {
        SOFTPV();                  // tile i-1 (V valid until STAGE below)
        vmwait<0>();
        __builtin_amdgcn_s_barrier();          // buf(i) ready; all done with buf^1
        __builtin_amdgcn_sched_barrier(0);
        if (i < 15) STAGE2();                  // tile i+1
        QKSAVE();                              // tile i (consumes mA)
        if (i < 15) LOADM();                   // mask tile i+1 -> mA
    }
    // ---- epilogue: tile 15 ----
    SOFTPV();
#undef STAGE2
#undef LOADM

    // deferred cross-lane l reduce (once)
    {
        float lA_ = __shfl_xor(l_run, 16);
        float lB_ = __shfl_xor(l_run, 32);
        float lC_ = __shfl_xor(l_run, 48);
        l_run = (l_run + lA_) + (lB_ + lC_);
    }

    // ---- merge group 1 partials into group 0, write out ----
    __syncthreads();
    float* oX = (float*)smem;                       // [64][68] padded f32
    float* mX = (float*)(smem + 64 * 68 * 4);       // [64]
    float* lX = mX + 64;

    if (grp == 1) {
#pragma unroll
        for (int g = 0; g < 4; ++g)
#pragma unroll
            for (int j = 0; j < 4; ++j)
                oX[(wq * 16 + 4 * hi + j) * 68 + g * 16 + ln] = o[g][j];
        if (hi == 0) { mX[wq * 16 + ln] = m_run; lX[wq * 16 + ln] = l_run; }
    }
    __syncthreads();
    if (grp == 0) {
#pragma unroll
        for (int j = 0; j < 4; ++j) {
            int q = 4 * hi + j;
            float mA = __shfl(m_run, q);
            float lA = __shfl(l_run, q);
            float mB = mX[wq * 16 + q];
            float lB = lX[wq * 16 + q];
            float mm = fmaxf(mA, mB);
            float aA = __builtin_amdgcn_exp2f(mA - mm);
            float aB = __builtin_amdgcn_exp2f(mB - mm);
            float inv = 1.0f / (lA * aA + lB * aB);
            aA *= inv; aB *= inv;
#pragma unroll
            for (int g = 0; g < 4; ++g) {
                float v = o[g][j] * aA + oX[(wq * 16 + q) * 68 + g * 16 + ln] * aB;
                long idx = ((long)b * L_ + q0 + q) * D_ + h * DH_ + g * 16 + ln;
                Og[idx] = f2bf(v);
            }
        }
    }
}

// ---------------- launch ----------------
extern "C" void kernel_launch(void* const* d_in, const int* in_sizes, int n_in,
                              void* d_out, int out_size, void* d_ws, size_t ws_size,
                              hipStream_t stream)
{
    const float* qx = (const float*)d_in[0];
    const float* kx = (const float*)d_in[1];
    const float* vx = (const float*)d_in[2];
    const float* ec = (const float*)d_in[3];
    const float* Wq = (const float*)d_in[4];
    const float* bq = (const float*)d_in[5];
    const float* Wk = (const float*)d_in[6];
    const float* bk = (const float*)d_in[7];
    const float* Wv = (const float*)d_in[8];
    const float* bv = (const float*)d_in[9];
    const float* Wo = (const float*)d_in[10];
    const float* bo = (const float*)d_in[11];
    float* out = (float*)d_out;

    const long NA = (long)B_ * L_ * D_;
    const long NW = (long)D_ * D_;

    unsigned short* Ap  = (unsigned short*)d_ws;   // attn output (bf16)
    unsigned short* wqb = Ap + NA;
    unsigned short* wkb = wqb + NW;
    unsigned short* wvb = wkb + NW;
    unsigned short* wob = wvb + NW;
    unsigned short* Qp  = wob + NW;
    unsigned short* Kp  = Qp + NA;
    unsigned short* Vtp = Kp + NA;       // V^T: [D][B*L], slot-swizzled
    float*          mk  = (float*)(Vtp + NA);

    const long nblk = (NW + B_ * L_ + 255) / 256;
    cvt_mask_kernel<<<dim3((unsigned)nblk), dim3(256), 0, stream>>>(
        Wq, Wk, Wv, Wo, ec, wqb, wkb, wvb, wob, mk);

    // fused QKV projections, A read directly as f32 (1536 blocks):
    // Q scaled, K plain, V transposed+swizzled
    GemmArgs zq = {qx, wqb, bq, Qp, 1};
    GemmArgs zk = {kx, wkb, bk, Kp, 0};
    GemmArgs zv = {vx, wvb, bv, Vtp, 2};
    gemm_kernel<64, 64, 1><<<dim3(8, 64, 3), dim3(256), 0, stream>>>(zq, zk, zv, B_ * L_, D_, D_);

    attn_kernel<<<dim3(L_ / 64, B_ * H_), dim3(512), 0, stream>>>(Qp, Kp, Vtp, mk, Ap);

    // output projection, bf16 A, f32 out (1024 blocks)
    GemmArgs zo = {Ap, wob, bo, out, 3};
    gemm_kernel<32, 64, 0><<<dim3(8, 128, 1), dim3(256), 0, stream>>>(zo, zo, zo, B_ * L_, D_, D_);
}

// Round 14
// 73.479 us; speedup vs baseline: 1.0034x; 1.0034x over previous
//
#include <hip/hip_runtime.h>
#include <stdint.h>

#define B_ 2
#define L_ 2048
#define D_ 512
#define H_ 8
#define DH_ 64

using frag8 = __attribute__((ext_vector_type(8))) short;   // 8 bf16 in 4 VGPRs
using bf4   = __attribute__((ext_vector_type(4))) short;   // 4 bf16 (one b64)
using f32x4 = __attribute__((ext_vector_type(4))) float;   // MFMA accumulator
using u32x4 = __attribute__((ext_vector_type(4))) unsigned int;

#define QSC 0.18033688011112042f   /* 0.125 * log2(e): exp2-domain scale folded into Q */

__device__ __forceinline__ unsigned short f2bf(float f) {
    unsigned int u = __float_as_uint(f);
    u += 0x7fffu + ((u >> 16) & 1u);      // RNE
    return (unsigned short)(u >> 16);
}

__device__ __forceinline__ unsigned int cvtpk(float lo, float hi_) {
    unsigned int r;
    asm("v_cvt_pk_bf16_f32 %0, %1, %2" : "=v"(r) : "v"(lo), "v"(hi_));
    return r;
}

__device__ __forceinline__ frag8 pk8(f32x4 lo, f32x4 hh) {
    union { u32x4 u; frag8 f; } v;
    v.u = (u32x4){cvtpk(lo[0], lo[1]), cvtpk(lo[2], lo[3]),
                  cvtpk(hh[0], hh[1]), cvtpk(hh[2], hh[3])};
    return v.f;
}

__device__ __forceinline__ void gl2lds16(const void* g, void* lds) {
    __builtin_amdgcn_global_load_lds((const __attribute__((address_space(1))) void*)g,
                                     (__attribute__((address_space(3))) void*)lds,
                                     16, 0, 0);
}

template<int N>
__device__ __forceinline__ void vmwait() {
    asm volatile("s_waitcnt vmcnt(%0)" :: "n"(N) : "memory");
}

// ---------------- prep: weight fp32 -> bf16 + energy mask ----------------
__global__ __launch_bounds__(256) void cvt_mask_kernel(
    const float* __restrict__ Wq, const float* __restrict__ Wk, const float* __restrict__ Wv,
    const float* __restrict__ Wo, const float* __restrict__ ec,
    unsigned short* wqb, unsigned short* wkb, unsigned short* wvb, unsigned short* wob,
    float* __restrict__ mk)
{
    const long NW = (long)D_ * D_;            // 262144
    long q4 = (long)blockIdx.x * 256 + threadIdx.x;
    if (q4 < NW) {                             // 4 matrices, 4 elems/thread
        long i = q4 * 4;
        int w = (int)(i / NW);
        long off = i - (long)w * NW;
        const float* src = (w == 0) ? Wq : (w == 1) ? Wk : (w == 2) ? Wv : Wo;
        unsigned short* dst = (w == 0) ? wqb : (w == 1) ? wkb : (w == 2) ? wvb : wob;
        float4 v = *(const float4*)(src + off);
        ushort4 o;
        o.x = f2bf(v.x); o.y = f2bf(v.y); o.z = f2bf(v.z); o.w = f2bf(v.w);
        *(ushort4*)(dst + off) = o;
    } else {
        long i = q4 - NW;                      // 0..B*L-1
        if (i < B_ * L_) {
            const float4* p4 = (const float4*)(ec + i * 16);
            float s = 0.0f;
#pragma unroll
            for (int j = 0; j < 4; ++j) {
                float4 v = p4[j];
                s += fabsf(v.x) + fabsf(v.y) + fabsf(v.z) + fabsf(v.w);
            }
            float energy = s * (1.0f / 16.0f);
            mk[i] = (energy > 0.1f) ? 0.0f : -1.0e9f;
        }
    }
}

// ---------------- GEMM: C[M,N] = A[M,K] * W[N,K]^T + bias ----------------
// Double-buffered LDS, counted-vmcnt pipeline, raw barriers, XCD-chunked swizzle,
// bias as MFMA C-init. AF32=1: A staged as f32 via global_load_lds, converted
// to bf16 at fragment-read time (v_cvt_pk_bf16_f32).
// mode 0: bf16 store; 1: bf16 * QSC (Q proj); 2: bf16 transposed V^T store with
// R5 slot swizzle (conflict-free b64 PV); 3: f32 store (out proj).
struct GemmArgs { const void* A; const unsigned short* W;
                  const float* bias; void* C; int mode; };

template<int BM, int BN, int AF32>
__global__ __launch_bounds__(256) void gemm_kernel(GemmArgs a0, GemmArgs a1, GemmArgs a2,
                                                   int M, int N, int K)
{
    // XCD-chunked swizzle (grid size divisible by 8 by construction)
    const int nwg = gridDim.x * gridDim.y * gridDim.z;
    int flat = blockIdx.x + gridDim.x * (blockIdx.y + gridDim.y * blockIdx.z);
    int swz  = (flat & 7) * (nwg >> 3) + (flat >> 3);
    const int bx = swz % gridDim.x;
    int t2 = swz / gridDim.x;
    const int by = t2 % gridDim.y;
    const int bz = t2 / gridDim.y;

    GemmArgs ga = bz == 0 ? a0 : (bz == 1 ? a1 : a2);
    const float* __restrict__ Af = (const float*)ga.A;
    const unsigned short* __restrict__ Ab = (const unsigned short*)ga.A;
    const unsigned short* __restrict__ W = ga.W;
    const float* __restrict__ bias = ga.bias;

    constexpr int MF = BM / 32;
    constexpr int NF = BN / 32;
    constexpr int NL = (AF32 ? BM / 16 : BM / 32) + BN / 32;

    __shared__ __align__(16) char sA[(size_t)2 * BM * 64 * (AF32 ? 4 : 2)];
    __shared__ __align__(16) unsigned short Bs[2][BN * 64];
    float* AsF = (float*)sA;
    unsigned short* As16 = (unsigned short*)sA;

    const int tid  = threadIdx.x;
    const int lane = tid & 63;
    const int wave = tid >> 6;
    const int hi   = lane >> 4;
    const int ln   = lane & 15;
    const int wr   = wave >> 1;
    const int wc   = wave & 1;

    const long mBase = (long)by * BM;
    const long nBase = (long)bx * BN;

    // bias as C-init (per output column)
    f32x4 acc[MF][NF];
#pragma unroll
    for (int n = 0; n < NF; ++n) {
        float bv = bias[nBase + wc * (BN / 2) + n * 16 + ln];
#pragma unroll
        for (int m = 0; m < MF; ++m) acc[m][n] = (f32x4){bv, bv, bv, bv};
    }

#define GSTAGE(KT, BUF) do {                                                    \
    if (AF32) {                                                                 \
        _Pragma("unroll")                                                       \
        for (int i_ = 0; i_ < BM / 16; ++i_) {       /* 16B chunks of f32 */    \
            int cl_ = i_ * 256 + tid;                                           \
            int r_ = cl_ >> 4, c_ = cl_ & 15, s_ = c_ ^ (r_ & 15);              \
            gl2lds16(Af + (mBase + r_) * K + (KT) + s_ * 4,                     \
                     AsF + ((BUF) * BM + r_) * 64 + (cl_ & 15) * 4);            \
        }                                                                       \
    } else {                                                                    \
        _Pragma("unroll")                                                       \
        for (int i_ = 0; i_ < BM / 32; ++i_) {                                  \
            int cl_ = i_ * 256 + tid;                                           \
            int r_ = cl_ >> 3, c_ = cl_ & 7, s_ = c_ ^ (r_ & 7);                \
            gl2lds16(Ab + (mBase + r_) * K + (KT) + s_ * 8,                     \
                     As16 + ((BUF) * BM + r_) * 64 + (cl_ & 7) * 8);            \
        }                                                                       \
    }                                                                           \
    _Pragma("unroll")                                                           \
    for (int i_ = 0; i_ < BN / 32; ++i_) {                                      \
        int cl_ = i_ * 256 + tid;                                               \
        int r_ = cl_ >> 3, c_ = cl_ & 7, s_ = c_ ^ (r_ & 7);                    \
        gl2lds16(W + (nBase + r_) * K + (KT) + s_ * 8, Bs[BUF] + cl_ * 8);      \
    }                                                                           \
} while (0)

    GSTAGE(0, 0);

    const int nk = K / 64;
    for (int t = 0; t < nk; ++t) {
        const int buf = t & 1;
        if (t + 1 < nk) {
            GSTAGE((t + 1) * 64, buf ^ 1);   // prefetch stays in flight across barriers
            vmwait<NL>();                     // wait only for tile t's loads
        } else {
            vmwait<0>();
        }
        __builtin_amdgcn_s_barrier();
        __builtin_amdgcn_sched_barrier(0);

        frag8 af[2][MF], bfr[2][NF];
#pragma unroll
        for (int kk = 0; kk < 2; ++kk) {
#pragma unroll
            for (int m = 0; m < MF; ++m) {
                int row = wr * (BM / 2) + m * 16 + ln;
                if (AF32) {
                    int c0 = kk * 8 + hi * 2;
                    int p0 = c0 ^ (row & 15);
                    int p1 = (c0 + 1) ^ (row & 15);
                    f32x4 lo = *(const f32x4*)(AsF + ((long)buf * BM + row) * 64 + p0 * 4);
                    f32x4 hh = *(const f32x4*)(AsF + ((long)buf * BM + row) * 64 + p1 * 4);
                    af[kk][m] = pk8(lo, hh);
                } else {
                    int c = (kk * 4 + hi) ^ (row & 7);
                    af[kk][m] = *(const frag8*)(As16 + ((long)buf * BM + row) * 64 + c * 8);
                }
            }
#pragma unroll
            for (int n = 0; n < NF; ++n) {
                int row = wc * (BN / 2) + n * 16 + ln;
                int c = (kk * 4 + hi) ^ (row & 7);
                bfr[kk][n] = *(const frag8*)(Bs[buf] + row * 64 + c * 8);
            }
        }
        __builtin_amdgcn_s_setprio(1);
#pragma unroll
        for (int kk = 0; kk < 2; ++kk)
#pragma unroll
            for (int m = 0; m < MF; ++m)
#pragma unroll
                for (int n = 0; n < NF; ++n)
                    acc[m][n] = __builtin_amdgcn_mfma_f32_16x16x32_bf16(af[kk][m], bfr[kk][n], acc[m][n], 0, 0, 0);
        __builtin_amdgcn_s_setprio(0);
        __builtin_amdgcn_sched_barrier(0);
        __builtin_amdgcn_s_barrier();        // raw: prefetch stays in flight
    }
#undef GSTAGE

    const int mode = ga.mode;
#pragma unroll
    for (int m = 0; m < MF; ++m) {
#pragma unroll
        for (int n = 0; n < NF; ++n) {
            long col = nBase + wc * (BN / 2) + n * 16 + ln;
#pragma unroll
            for (int j = 0; j < 4; ++j) {
                long row = mBase + wr * (BM / 2) + m * 16 + hi * 4 + j;
                float v = acc[m][n][j];
                if (mode == 3) {
                    ((float*)ga.C)[row * N + col] = v;
                } else if (mode == 2) {
                    // V^T store: R5 slot swizzle (key-group s at s^sw within 64)
                    int dh = (int)col & 63;
                    int swv = ((dh & 7) << 1) | ((dh >> 3) & 1);
                    long nt = (row & ~63L) | (long)(((((int)(row >> 2)) & 15) ^ swv) << 2) | (row & 3);
                    ((unsigned short*)ga.C)[col * (long)(B_ * L_) + nt] = f2bf(v);
                } else {
                    if (mode == 1) v *= QSC;
                    ((unsigned short*)ga.C)[row * N + col] = f2bf(v);
                }
            }
        }
    }
}

// ---------------- fused flash attention ----------------
// grid (L/64, B*H) with XCD-chunked remap. 512 thr = 8 waves; groups 0/1 =
// even/odd 64-key tiles, double-buffered K/V, DEFERRED softmax/PV, ONE barrier
// per iter. All global pointers strength-reduced (incremental); LDS buffers
// via ^8192 offset toggle; per-lane l accumulated, cross-lane reduced ONCE at
// end. Mask = MFMA C-init (registers, prefetched a tile ahead). exp2-domain
// softmax, defer-max THR=8. V^T slot-swizzled in global: conflict-free b64 PV.
__global__ __launch_bounds__(512, 4) void attn_kernel(
    const unsigned short* __restrict__ Qg, const unsigned short* __restrict__ Kg,
    const unsigned short* __restrict__ Vt, const float* __restrict__ mkg,
    unsigned short* __restrict__ Og)
{
    const int tid  = threadIdx.x;
    const int lane = tid & 63;
    const int wave = tid >> 6;
    const int grp  = wave >> 2;
    const int wq   = wave & 3;
    const int gtid = tid & 255;
    const int hi   = lane >> 4;
    const int ln   = lane & 15;

    // XCD-chunked remap: XCD x owns heads {2x, 2x+1}
    const int flat = blockIdx.x + gridDim.x * blockIdx.y;
    const int nwg  = gridDim.x * gridDim.y;
    const int s    = (flat & 7) * (nwg >> 3) + (flat >> 3);
    const int qt   = s & (gridDim.x - 1);
    const int bh   = s / gridDim.x;

    const int b  = bh >> 3, h = bh & 7;
    const unsigned short* Qb = Qg + ((long)b * L_) * D_ + h * DH_;
    const unsigned short* Kb = Kg + ((long)b * L_) * D_ + h * DH_;
    const unsigned short* Vb = Vt + (long)(h * DH_) * (B_ * L_) + (long)b * L_;
    const float* mkb = mkg + (long)b * L_;

    __shared__ __align__(16) char smem[65536];
    unsigned short* KsG = (unsigned short*)(smem + grp * 32768);
    unsigned short* VsG = (unsigned short*)(smem + grp * 32768 + 16384);

    const int q0 = qt * 64 + wq * 16;

    frag8 qf[2];
#pragma unroll
    for (int ks = 0; ks < 2; ++ks)
        qf[ks] = *(const frag8*)(Qb + (long)(q0 + ln) * D_ + ks * 32 + hi * 8);

    // ---- incremental global stage pointers (advance 2 tiles / iter) ----
    const int r0 = gtid >> 3, c0 = gtid & 7;
    const unsigned short* kg0 = Kb + (long)(grp * 64 + r0) * D_ + ((c0 ^ (r0 & 7)) << 3);
    const unsigned short* kg1 = kg0 + 32 * D_;
    const unsigned short* vg0 = Vb + (long)r0 * (B_ * L_) + grp * 64 + (c0 << 3);
    const unsigned short* vg1 = vg0 + (long)32 * (B_ * L_);
    const float* mp = mkb + grp * 64 + 4 * hi;

    // LDS staging destinations (toggle ^8192 bytes after each STAGE)
    unsigned short* kd0 = KsG + gtid * 8;
    unsigned short* kd1 = KsG + 2048 + gtid * 8;
    unsigned short* vd0 = VsG + gtid * 8;
    unsigned short* vd1 = VsG + 2048 + gtid * 8;

    // lane-fixed LDS read bases + buffer byte-offset toggles
    const int sw = ((ln & 7) << 1) | ((ln >> 3) & 1);
    const char* krp0 = (const char*)KsG + ln * 128 + ((hi ^ (ln & 7)) << 4);
    const char* krp1 = (const char*)KsG + ln * 128 + (((4 + hi) ^ (ln & 7)) << 4);
    const char* vrp0 = (const char*)VsG + ln * 128 + (((hi     ) ^ sw) << 3);
    const char* vrp1 = (const char*)VsG + ln * 128 + (((hi + 4 ) ^ sw) << 3);
    const char* vrp2 = (const char*)VsG + ln * 128 + (((hi + 8 ) ^ sw) << 3);
    const char* vrp3 = (const char*)VsG + ln * 128 + (((hi + 12) ^ sw) << 3);
    int kbo = 0, vbo = 0;

#define STAGE2() do {                                                           \
    gl2lds16(kg0, kd0); gl2lds16(vg0, vd0);                                     \
    gl2lds16(kg1, kd1); gl2lds16(vg1, vd1);                                     \
    kg0 += 128 * D_; kg1 += 128 * D_; vg0 += 128; vg1 += 128;                   \
    kd0 = (unsigned short*)((uintptr_t)kd0 ^ 8192);                             \
    kd1 = (unsigned short*)((uintptr_t)kd1 ^ 8192);                             \
    vd0 = (unsigned short*)((uintptr_t)vd0 ^ 8192);                             \
    vd1 = (unsigned short*)((uintptr_t)vd1 ^ 8192);                             \
} while (0)

    f32x4 o[4];
#pragma unroll
    for (int g = 0; g < 4; ++g) o[g] = (f32x4){0.f, 0.f, 0.f, 0.f};
    float m_run = -__builtin_inff();
    float l_run = 0.0f;            // per-lane partial; reduced once at end
    f32x4 scp[4];                  // deferred masked scores (previous tile)
    f32x4 mA0, mA1, mA2, mA3;      // mask regs (C-init source)

#define LOADM() do {                                                            \
    mA0 = *(const f32x4*)(mp);                                                  \
    mA1 = *(const f32x4*)(mp + 16);                                             \
    mA2 = *(const f32x4*)(mp + 32);                                             \
    mA3 = *(const f32x4*)(mp + 48);                                             \
    mp += 128;                                                                  \
} while (0)

    // deferred softmax + PV on scp (per-lane l, no cross-lane l reduce)
    auto SOFTPV = [&]() {
        float a0 = fmaxf(fmaxf(scp[0][0], scp[0][1]), fmaxf(scp[0][2], scp[0][3]));
        float a1 = fmaxf(fmaxf(scp[1][0], scp[1][1]), fmaxf(scp[1][2], scp[1][3]));
        float a2 = fmaxf(fmaxf(scp[2][0], scp[2][1]), fmaxf(scp[2][2], scp[2][3]));
        float a3 = fmaxf(fmaxf(scp[3][0], scp[3][1]), fmaxf(scp[3][2], scp[3][3]));
        float tl = fmaxf(fmaxf(a0, a1), fmaxf(a2, a3));
        float tA = __shfl_xor(tl, 16);
        float tB = __shfl_xor(tl, 32);
        float tC = __shfl_xor(tl, 48);
        float tmax = fmaxf(fmaxf(tl, tA), fmaxf(tB, tC));

        if (!__all(tmax <= m_run + 8.0f)) {
            float m_new = fmaxf(m_run, tmax);
            float alpha = __builtin_amdgcn_exp2f(m_run - m_new);
            float b0 = __shfl(alpha, 4 * hi + 0);
            float b1 = __shfl(alpha, 4 * hi + 1);
            float b2 = __shfl(alpha, 4 * hi + 2);
            float b3 = __shfl(alpha, 4 * hi + 3);
#pragma unroll
            for (int g = 0; g < 4; ++g) {
                o[g][0] *= b0; o[g][1] *= b1; o[g][2] *= b2; o[g][3] *= b3;
            }
            l_run *= alpha;
            m_run = m_new;
        }

        float p[16];
#pragma unroll
        for (int sh = 0; sh < 4; ++sh)
#pragma unroll
            for (int r = 0; r < 4; ++r)
                p[sh * 4 + r] = __builtin_amdgcn_exp2f(scp[sh][r] - m_run);
        float s01 = (p[0] + p[1]) + (p[2] + p[3]);
        float s23 = (p[4] + p[5]) + (p[6] + p[7]);
        float s45 = (p[8] + p[9]) + (p[10] + p[11]);
        float s67 = (p[12] + p[13]) + (p[14] + p[15]);
        l_run += (s01 + s23) + (s45 + s67);

        union PU { u32x4 u; frag8 f; } p0u, p1u;
        p0u.u = (u32x4){cvtpk(p[0], p[1]),  cvtpk(p[2], p[3]),
                        cvtpk(p[4], p[5]),  cvtpk(p[6], p[7])};
        p1u.u = (u32x4){cvtpk(p[8], p[9]),  cvtpk(p[10], p[11]),
                        cvtpk(p[12], p[13]), cvtpk(p[14], p[15])};

        __builtin_amdgcn_s_setprio(1);
#pragma unroll
        for (int g = 0; g < 4; ++g) {
            bf4 v0 = *(const bf4*)(vrp0 + vbo + g * 2048);
            bf4 v1 = *(const bf4*)(vrp1 + vbo + g * 2048);
            bf4 v2 = *(const bf4*)(vrp2 + vbo + g * 2048);
            bf4 v3 = *(const bf4*)(vrp3 + vbo + g * 2048);
            frag8 vf0 = __builtin_shufflevector(v0, v1, 0, 1, 2, 3, 4, 5, 6, 7);
            frag8 vf1 = __builtin_shufflevector(v2, v3, 0, 1, 2, 3, 4, 5, 6, 7);
            o[g] = __builtin_amdgcn_mfma_f32_16x16x32_bf16(p0u.f, vf0, o[g], 0, 0, 0);
            o[g] = __builtin_amdgcn_mfma_f32_16x16x32_bf16(p1u.f, vf1, o[g], 0, 0, 0);
        }
        __builtin_amdgcn_s_setprio(0);
        vbo ^= 8192;
    };

    // QK^T of current K buffer; mask regs enter as MFMA C-init; result -> scp
    auto QKSAVE = [&]() {
        scp[0] = mA0; scp[1] = mA1; scp[2] = mA2; scp[3] = mA3;
        __builtin_amdgcn_s_setprio(1);
#pragma unroll
        for (int sh = 0; sh < 4; ++sh) {
            frag8 k0 = *(const frag8*)(krp0 + kbo + sh * 2048);
            frag8 k1 = *(const frag8*)(krp1 + kbo + sh * 2048);
            scp[sh] = __builtin_amdgcn_mfma_f32_16x16x32_bf16(k0, qf[0], scp[sh], 0, 0, 0);
            scp[sh] = __builtin_amdgcn_mfma_f32_16x16x32_bf16(k1, qf[1], scp[sh], 0, 0, 0);
        }
        __builtin_amdgcn_s_setprio(0);
        kbo ^= 8192;
    };

    // ---- iteration 0 (peeled) ----
    STAGE2();                      // tile 0 -> buf 0
    LOADM();                       // mask tile 0 -> mA
    vmwait<0>();
    __builtin_amdgcn_s_barrier();
    __builtin_amdgcn_sched_barrier(0);
    STAGE2();                      // tile 1 -> buf 1
    QKSAVE();                      // tile 0 (consumes mA)
    LOADM();                       // mask tile 1 -> mA

    // ---- steady state ----
    for (int i = 1; i < 16; ++i) {
        SOFTPV();                  // tile i-1 (V valid until STAGE below)
        vmwait<0>();
        __builtin_amdgcn_s_barrier();          // buf(i) ready; all done with buf^1
        __builtin_amdgcn_sched_barrier(0);
        if (i < 15) STAGE2();                  // tile i+1
        QKSAVE();                              // tile i (consumes mA)
        if (i < 15) LOADM();                   // mask tile i+1 -> mA
    }
    // ---- epilogue: tile 15 ----
    SOFTPV();
#undef STAGE2
#undef LOADM

    // deferred cross-lane l reduce (once)
    {
        float lA_ = __shfl_xor(l_run, 16);
        float lB_ = __shfl_xor(l_run, 32);
        float lC_ = __shfl_xor(l_run, 48);
        l_run = (l_run + lA_) + (lB_ + lC_);
    }

    // ---- merge group 1 partials into group 0, write out ----
    __syncthreads();
    float* oX = (float*)smem;                       // [64][68] padded f32
    float* mX = (float*)(smem + 64 * 68 * 4);       // [64]
    float* lX = mX + 64;

    if (grp == 1) {
#pragma unroll
        for (int g = 0; g < 4; ++g)
#pragma unroll
            for (int j = 0; j < 4; ++j)
                oX[(wq * 16 + 4 * hi + j) * 68 + g * 16 + ln] = o[g][j];
        if (hi == 0) { mX[wq * 16 + ln] = m_run; lX[wq * 16 + ln] = l_run; }
    }
    __syncthreads();
    if (grp == 0) {
#pragma unroll
        for (int j = 0; j < 4; ++j) {
            int q = 4 * hi + j;
            float mA = __shfl(m_run, q);
            float lA = __shfl(l_run, q);
            float mB = mX[wq * 16 + q];
            float lB = lX[wq * 16 + q];
            float mm = fmaxf(mA, mB);
            float aA = __builtin_amdgcn_exp2f(mA - mm);
            float aB = __builtin_amdgcn_exp2f(mB - mm);
            float inv = 1.0f / (lA * aA + lB * aB);
            aA *= inv; aB *= inv;
#pragma unroll
            for (int g = 0; g < 4; ++g) {
                float v = o[g][j] * aA + oX[(wq * 16 + q) * 68 + g * 16 + ln] * aB;
                long idx = ((long)b * L_ + q0 + q) * D_ + h * DH_ + g * 16 + ln;
                Og[idx] = f2bf(v);
            }
        }
    }
}

// ---------------- launch ----------------
extern "C" void kernel_launch(void* const* d_in, const int* in_sizes, int n_in,
                              void* d_out, int out_size, void* d_ws, size_t ws_size,
                              hipStream_t stream)
{
    const float* qx = (const float*)d_in[0];
    const float* kx = (const float*)d_in[1];
    const float* vx = (const float*)d_in[2];
    const float* ec = (const float*)d_in[3];
    const float* Wq = (const float*)d_in[4];
    const float* bq = (const float*)d_in[5];
    const float* Wk = (const float*)d_in[6];
    const float* bk = (const float*)d_in[7];
    const float* Wv = (const float*)d_in[8];
    const float* bv = (const float*)d_in[9];
    const float* Wo = (const float*)d_in[10];
    const float* bo = (const float*)d_in[11];
    float* out = (float*)d_out;

    const long NA = (long)B_ * L_ * D_;
    const long NW = (long)D_ * D_;

    unsigned short* Ap  = (unsigned short*)d_ws;   // attn output (bf16)
    unsigned short* wqb = Ap + NA;
    unsigned short* wkb = wqb + NW;
    unsigned short* wvb = wkb + NW;
    unsigned short* wob = wvb + NW;
    unsigned short* Qp  = wob + NW;
    unsigned short* Kp  = Qp + NA;
    unsigned short* Vtp = Kp + NA;       // V^T: [D][B*L], slot-swizzled
    float*          mk  = (float*)(Vtp + NA);

    const long nblk = (NW + B_ * L_ + 255) / 256;
    cvt_mask_kernel<<<dim3((unsigned)nblk), dim3(256), 0, stream>>>(
        Wq, Wk, Wv, Wo, ec, wqb, wkb, wvb, wob, mk);

    // fused QKV projections, A read directly as f32 (1536 blocks):
    // Q scaled, K plain, V transposed+swizzled
    GemmArgs zq = {qx, wqb, bq, Qp, 1};
    GemmArgs zk = {kx, wkb, bk, Kp, 0};
    GemmArgs zv = {vx, wvb, bv, Vtp, 2};
    gemm_kernel<64, 64, 1><<<dim3(8, 64, 3), dim3(256), 0, stream>>>(zq, zk, zv, B_ * L_, D_, D_);

    attn_kernel<<<dim3(L_ / 64, B_ * H_), dim3(512), 0, stream>>>(Qp, Kp, Vtp, mk, Ap);

    // output projection, bf16 A, f32 out (1024 blocks)
    GemmArgs zo = {Ap, wob, bo, out, 3};
    gemm_kernel<32, 64, 0><<<dim3(8, 128, 1), dim3(256), 0, stream>>>(zo, zo, zo, B_ * L_, D_, D_);
}

// Round 15
// 73.334 us; speedup vs baseline: 1.0054x; 1.0020x over previous
//
#include <hip/hip_runtime.h>
#include <stdint.h>

#define B_ 2
#define L_ 2048
#define D_ 512
#define H_ 8
#define DH_ 64

using frag8 = __attribute__((ext_vector_type(8))) short;   // 8 bf16 in 4 VGPRs
using bf4   = __attribute__((ext_vector_type(4))) short;   // 4 bf16 (one b64)
using f32x4 = __attribute__((ext_vector_type(4))) float;   // MFMA accumulator
using u32x4 = __attribute__((ext_vector_type(4))) unsigned int;

#define QSC 0.18033688011112042f   /* 0.125 * log2(e): exp2-domain scale folded into Q */

__device__ __forceinline__ unsigned short f2bf(float f) {
    unsigned int u = __float_as_uint(f);
    u += 0x7fffu + ((u >> 16) & 1u);      // RNE
    return (unsigned short)(u >> 16);
}

__device__ __forceinline__ unsigned int cvtpk(float lo, float hi_) {
    unsigned int r;
    asm("v_cvt_pk_bf16_f32 %0, %1, %2" : "=v"(r) : "v"(lo), "v"(hi_));
    return r;
}

__device__ __forceinline__ frag8 pk8(f32x4 lo, f32x4 hh) {
    union { u32x4 u; frag8 f; } v;
    v.u = (u32x4){cvtpk(lo[0], lo[1]), cvtpk(lo[2], lo[3]),
                  cvtpk(hh[0], hh[1]), cvtpk(hh[2], hh[3])};
    return v.f;
}

__device__ __forceinline__ void gl2lds16(const void* g, void* lds) {
    __builtin_amdgcn_global_load_lds((const __attribute__((address_space(1))) void*)g,
                                     (__attribute__((address_space(3))) void*)lds,
                                     16, 0, 0);
}

template<int N>
__device__ __forceinline__ void vmwait() {
    asm volatile("s_waitcnt vmcnt(%0)" :: "n"(N) : "memory");
}

// ---------------- prep: weight fp32 -> bf16 + energy mask ----------------
__global__ __launch_bounds__(256) void cvt_mask_kernel(
    const float* __restrict__ Wq, const float* __restrict__ Wk, const float* __restrict__ Wv,
    const float* __restrict__ Wo, const float* __restrict__ ec,
    unsigned short* wqb, unsigned short* wkb, unsigned short* wvb, unsigned short* wob,
    float* __restrict__ mk)
{
    const long NW = (long)D_ * D_;            // 262144
    long q4 = (long)blockIdx.x * 256 + threadIdx.x;
    if (q4 < NW) {                             // 4 matrices, 4 elems/thread
        long i = q4 * 4;
        int w = (int)(i / NW);
        long off = i - (long)w * NW;
        const float* src = (w == 0) ? Wq : (w == 1) ? Wk : (w == 2) ? Wv : Wo;
        unsigned short* dst = (w == 0) ? wqb : (w == 1) ? wkb : (w == 2) ? wvb : wob;
        float4 v = *(const float4*)(src + off);
        ushort4 o;
        o.x = f2bf(v.x); o.y = f2bf(v.y); o.z = f2bf(v.z); o.w = f2bf(v.w);
        *(ushort4*)(dst + off) = o;
    } else {
        long i = q4 - NW;                      // 0..B*L-1
        if (i < B_ * L_) {
            const float4* p4 = (const float4*)(ec + i * 16);
            float s = 0.0f;
#pragma unroll
            for (int j = 0; j < 4; ++j) {
                float4 v = p4[j];
                s += fabsf(v.x) + fabsf(v.y) + fabsf(v.z) + fabsf(v.w);
            }
            float energy = s * (1.0f / 16.0f);
            mk[i] = (energy > 0.1f) ? 0.0f : -1.0e9f;
        }
    }
}

// ---------------- GEMM: C[M,N] = A[M,K] * W[N,K]^T + bias ----------------
// Double-buffered LDS, counted-vmcnt pipeline, raw barriers, XCD-chunked swizzle,
// bias as MFMA C-init. AF32=1: A staged as f32 via global_load_lds, converted
// to bf16 at fragment-read time (v_cvt_pk_bf16_f32).
// mode 0: bf16 store; 1: bf16 * QSC (Q proj); 2: bf16 transposed V^T store with
// R5 slot swizzle (conflict-free b64 PV); 3: f32 store (out proj).
struct GemmArgs { const void* A; const unsigned short* W;
                  const float* bias; void* C; int mode; };

template<int BM, int BN, int AF32>
__global__ __launch_bounds__(256) void gemm_kernel(GemmArgs a0, GemmArgs a1, GemmArgs a2,
                                                   int M, int N, int K)
{
    // XCD-chunked swizzle (grid size divisible by 8 by construction)
    const int nwg = gridDim.x * gridDim.y * gridDim.z;
    int flat = blockIdx.x + gridDim.x * (blockIdx.y + gridDim.y * blockIdx.z);
    int swz  = (flat & 7) * (nwg >> 3) + (flat >> 3);
    const int bx = swz % gridDim.x;
    int t2 = swz / gridDim.x;
    const int by = t2 % gridDim.y;
    const int bz = t2 / gridDim.y;

    GemmArgs ga = bz == 0 ? a0 : (bz == 1 ? a1 : a2);
    const float* __restrict__ Af = (const float*)ga.A;
    const unsigned short* __restrict__ Ab = (const unsigned short*)ga.A;
    const unsigned short* __restrict__ W = ga.W;
    const float* __restrict__ bias = ga.bias;

    constexpr int MF = BM / 32;
    constexpr int NF = BN / 32;
    constexpr int NL = (AF32 ? BM / 16 : BM / 32) + BN / 32;

    __shared__ __align__(16) char sA[(size_t)2 * BM * 64 * (AF32 ? 4 : 2)];
    __shared__ __align__(16) unsigned short Bs[2][BN * 64];
    float* AsF = (float*)sA;
    unsigned short* As16 = (unsigned short*)sA;

    const int tid  = threadIdx.x;
    const int lane = tid & 63;
    const int wave = tid >> 6;
    const int hi   = lane >> 4;
    const int ln   = lane & 15;
    const int wr   = wave >> 1;
    const int wc   = wave & 1;

    const long mBase = (long)by * BM;
    const long nBase = (long)bx * BN;

    // bias as C-init (per output column)
    f32x4 acc[MF][NF];
#pragma unroll
    for (int n = 0; n < NF; ++n) {
        float bv = bias[nBase + wc * (BN / 2) + n * 16 + ln];
#pragma unroll
        for (int m = 0; m < MF; ++m) acc[m][n] = (f32x4){bv, bv, bv, bv};
    }

#define GSTAGE(KT, BUF) do {                                                    \
    if (AF32) {                                                                 \
        _Pragma("unroll")                                                       \
        for (int i_ = 0; i_ < BM / 16; ++i_) {       /* 16B chunks of f32 */    \
            int cl_ = i_ * 256 + tid;                                           \
            int r_ = cl_ >> 4, c_ = cl_ & 15, s_ = c_ ^ (r_ & 15);              \
            gl2lds16(Af + (mBase + r_) * K + (KT) + s_ * 4,                     \
                     AsF + ((BUF) * BM + r_) * 64 + (cl_ & 15) * 4);            \
        }                                                                       \
    } else {                                                                    \
        _Pragma("unroll")                                                       \
        for (int i_ = 0; i_ < BM / 32; ++i_) {                                  \
            int cl_ = i_ * 256 + tid;                                           \
            int r_ = cl_ >> 3, c_ = cl_ & 7, s_ = c_ ^ (r_ & 7);                \
            gl2lds16(Ab + (mBase + r_) * K + (KT) + s_ * 8,                     \
                     As16 + ((BUF) * BM + r_) * 64 + (cl_ & 7) * 8);            \
        }                                                                       \
    }                                                                           \
    _Pragma("unroll")                                                           \
    for (int i_ = 0; i_ < BN / 32; ++i_) {                                      \
        int cl_ = i_ * 256 + tid;                                               \
        int r_ = cl_ >> 3, c_ = cl_ & 7, s_ = c_ ^ (r_ & 7);                    \
        gl2lds16(W + (nBase + r_) * K + (KT) + s_ * 8, Bs[BUF] + cl_ * 8);      \
    }                                                                           \
} while (0)

    GSTAGE(0, 0);

    const int nk = K / 64;
    for (int t = 0; t < nk; ++t) {
        const int buf = t & 1;
        if (t + 1 < nk) {
            GSTAGE((t + 1) * 64, buf ^ 1);   // prefetch stays in flight across barriers
            vmwait<NL>();                     // wait only for tile t's loads
        } else {
            vmwait<0>();
        }
        __builtin_amdgcn_s_barrier();
        __builtin_amdgcn_sched_barrier(0);

        frag8 af[2][MF], bfr[2][NF];
#pragma unroll
        for (int kk = 0; kk < 2; ++kk) {
#pragma unroll
            for (int m = 0; m < MF; ++m) {
                int row = wr * (BM / 2) + m * 16 + ln;
                if (AF32) {
                    int c0 = kk * 8 + hi * 2;
                    int p0 = c0 ^ (row & 15);
                    int p1 = (c0 + 1) ^ (row & 15);
                    f32x4 lo = *(const f32x4*)(AsF + ((long)buf * BM + row) * 64 + p0 * 4);
                    f32x4 hh = *(const f32x4*)(AsF + ((long)buf * BM + row) * 64 + p1 * 4);
                    af[kk][m] = pk8(lo, hh);
                } else {
                    int c = (kk * 4 + hi) ^ (row & 7);
                    af[kk][m] = *(const frag8*)(As16 + ((long)buf * BM + row) * 64 + c * 8);
                }
            }
#pragma unroll
            for (int n = 0; n < NF; ++n) {
                int row = wc * (BN / 2) + n * 16 + ln;
                int c = (kk * 4 + hi) ^ (row & 7);
                bfr[kk][n] = *(const frag8*)(Bs[buf] + row * 64 + c * 8);
            }
        }
        __builtin_amdgcn_s_setprio(1);
#pragma unroll
        for (int kk = 0; kk < 2; ++kk)
#pragma unroll
            for (int m = 0; m < MF; ++m)
#pragma unroll
                for (int n = 0; n < NF; ++n)
                    acc[m][n] = __builtin_amdgcn_mfma_f32_16x16x32_bf16(af[kk][m], bfr[kk][n], acc[m][n], 0, 0, 0);
        __builtin_amdgcn_s_setprio(0);
        __builtin_amdgcn_sched_barrier(0);
        __builtin_amdgcn_s_barrier();        // raw: prefetch stays in flight
    }
#undef GSTAGE

    const int mode = ga.mode;
#pragma unroll
    for (int m = 0; m < MF; ++m) {
#pragma unroll
        for (int n = 0; n < NF; ++n) {
            long col = nBase + wc * (BN / 2) + n * 16 + ln;
#pragma unroll
            for (int j = 0; j < 4; ++j) {
                long row = mBase + wr * (BM / 2) + m * 16 + hi * 4 + j;
                float v = acc[m][n][j];
                if (mode == 3) {
                    ((float*)ga.C)[row * N + col] = v;
                } else if (mode == 2) {
                    // V^T store: R5 slot swizzle (key-group s at s^sw within 64)
                    int dh = (int)col & 63;
                    int swv = ((dh & 7) << 1) | ((dh >> 3) & 1);
                    long nt = (row & ~63L) | (long)(((((int)(row >> 2)) & 15) ^ swv) << 2) | (row & 3);
                    ((unsigned short*)ga.C)[col * (long)(B_ * L_) + nt] = f2bf(v);
                } else {
                    if (mode == 1) v *= QSC;
                    ((unsigned short*)ga.C)[row * N + col] = f2bf(v);
                }
            }
        }
    }
}

// ---------------- fused flash attention ----------------
// grid (L/64, B*H) with XCD-chunked remap. 512 thr = 8 waves; groups 0/1 =
// even/odd 64-key tiles, double-buffered K/V, DEFERRED softmax/PV, ONE barrier
// per iter. All global pointers strength-reduced (incremental); LDS buffers
// via ^8192 offset toggle; per-lane l accumulated, cross-lane reduced ONCE at
// end. Mask = MFMA C-init (registers, prefetched a tile ahead). exp2-domain
// softmax, defer-max THR=8. V^T slot-swizzled in global: conflict-free b64 PV.
__global__ __launch_bounds__(512, 4) void attn_kernel(
    const unsigned short* __restrict__ Qg, const unsigned short* __restrict__ Kg,
    const unsigned short* __restrict__ Vt, const float* __restrict__ mkg,
    unsigned short* __restrict__ Og)
{
    const int tid  = threadIdx.x;
    const int lane = tid & 63;
    const int wave = tid >> 6;
    const int grp  = wave >> 2;
    const int wq   = wave & 3;
    const int gtid = tid & 255;
    const int hi   = lane >> 4;
    const int ln   = lane & 15;

    // XCD-chunked remap: XCD x owns heads {2x, 2x+1}
    const int flat = blockIdx.x + gridDim.x * blockIdx.y;
    const int nwg  = gridDim.x * gridDim.y;
    const int s    = (flat & 7) * (nwg >> 3) + (flat >> 3);
    const int qt   = s & (gridDim.x - 1);
    const int bh   = s / gridDim.x;

    const int b  = bh >> 3, h = bh & 7;
    const unsigned short* Qb = Qg + ((long)b * L_) * D_ + h * DH_;
    const unsigned short* Kb = Kg + ((long)b * L_) * D_ + h * DH_;
    const unsigned short* Vb = Vt + (long)(h * DH_) * (B_ * L_) + (long)b * L_;
    const float* mkb = mkg + (long)b * L_;

    __shared__ __align__(16) char smem[65536];
    unsigned short* KsG = (unsigned short*)(smem + grp * 32768);
    unsigned short* VsG = (unsigned short*)(smem + grp * 32768 + 16384);

    const int q0 = qt * 64 + wq * 16;

    frag8 qf[2];
#pragma unroll
    for (int ks = 0; ks < 2; ++ks)
        qf[ks] = *(const frag8*)(Qb + (long)(q0 + ln) * D_ + ks * 32 + hi * 8);

    // ---- incremental global stage pointers (advance 2 tiles / iter) ----
    const int r0 = gtid >> 3, c0 = gtid & 7;
    const unsigned short* kg0 = Kb + (long)(grp * 64 + r0) * D_ + ((c0 ^ (r0 & 7)) << 3);
    const unsigned short* kg1 = kg0 + 32 * D_;
    const unsigned short* vg0 = Vb + (long)r0 * (B_ * L_) + grp * 64 + (c0 << 3);
    const unsigned short* vg1 = vg0 + (long)32 * (B_ * L_);
    const float* mp = mkb + grp * 64 + 4 * hi;

    // LDS staging destinations (toggle ^8192 bytes after each STAGE)
    unsigned short* kd0 = KsG + gtid * 8;
    unsigned short* kd1 = KsG + 2048 + gtid * 8;
    unsigned short* vd0 = VsG + gtid * 8;
    unsigned short* vd1 = VsG + 2048 + gtid * 8;

    // lane-fixed LDS read bases + buffer byte-offset toggles
    const int sw = ((ln & 7) << 1) | ((ln >> 3) & 1);
    const char* krp0 = (const char*)KsG + ln * 128 + ((hi ^ (ln & 7)) << 4);
    const char* krp1 = (const char*)KsG + ln * 128 + (((4 + hi) ^ (ln & 7)) << 4);
    const char* vrp0 = (const char*)VsG + ln * 128 + (((hi     ) ^ sw) << 3);
    const char* vrp1 = (const char*)VsG + ln * 128 + (((hi + 4 ) ^ sw) << 3);
    const char* vrp2 = (const char*)VsG + ln * 128 + (((hi + 8 ) ^ sw) << 3);
    const char* vrp3 = (const char*)VsG + ln * 128 + (((hi + 12) ^ sw) << 3);
    int kbo = 0, vbo = 0;

#define STAGE2() do {                                                           \
    gl2lds16(kg0, kd0); gl2lds16(vg0, vd0);                                     \
    gl2lds16(kg1, kd1); gl2lds16(vg1, vd1);                                     \
    kg0 += 128 * D_; kg1 += 128 * D_; vg0 += 128; vg1 += 128;                   \
    kd0 = (unsigned short*)((uintptr_t)kd0 ^ 8192);                             \
    kd1 = (unsigned short*)((uintptr_t)kd1 ^ 8192);                             \
    vd0 = (unsigned short*)((uintptr_t)vd0 ^ 8192);                             \
    vd1 = (unsigned short*)((uintptr_t)vd1 ^ 8192);                             \
} while (0)

    f32x4 o[4];
#pragma unroll
    for (int g = 0; g < 4; ++g) o[g] = (f32x4){0.f, 0.f, 0.f, 0.f};
    float m_run = -__builtin_inff();
    float l_run = 0.0f;            // per-lane partial; reduced once at end
    f32x4 scp[4];                  // deferred masked scores (previous tile)
    f32x4 mA0, mA1, mA2, mA3;      // mask regs (C-init source)

#define LOADM() do {                                                            \
    mA0 = *(const f32x4*)(mp);                                                  \
    mA1 = *(const f32x4*)(mp + 16);                                             \
    mA2 = *(const f32x4*)(mp + 32);                                             \
    mA3 = *(const f32x4*)(mp + 48);                                             \
    mp += 128;                                                                  \
} while (0)

    // deferred softmax + PV on scp (per-lane l, no cross-lane l reduce)
    auto SOFTPV = [&]() {
        float a0 = fmaxf(fmaxf(scp[0][0], scp[0][1]), fmaxf(scp[0][2], scp[0][3]));
        float a1 = fmaxf(fmaxf(scp[1][0], scp[1][1]), fmaxf(scp[1][2], scp[1][3]));
        float a2 = fmaxf(fmaxf(scp[2][0], scp[2][1]), fmaxf(scp[2][2], scp[2][3]));
        float a3 = fmaxf(fmaxf(scp[3][0], scp[3][1]), fmaxf(scp[3][2], scp[3][3]));
        float tl = fmaxf(fmaxf(a0, a1), fmaxf(a2, a3));
        float tA = __shfl_xor(tl, 16);
        float tB = __shfl_xor(tl, 32);
        float tC = __shfl_xor(tl, 48);
        float tmax = fmaxf(fmaxf(tl, tA), fmaxf(tB, tC));

        if (!__all(tmax <= m_run + 8.0f)) {
            float m_new = fmaxf(m_run, tmax);
            float alpha = __builtin_amdgcn_exp2f(m_run - m_new);
            float b0 = __shfl(alpha, 4 * hi + 0);
            float b1 = __shfl(alpha, 4 * hi + 1);
            float b2 = __shfl(alpha, 4 * hi + 2);
            float b3 = __shfl(alpha, 4 * hi + 3);
#pragma unroll
            for (int g = 0; g < 4; ++g) {
                o[g][0] *= b0; o[g][1] *= b1; o[g][2] *= b2; o[g][3] *= b3;
            }
            l_run *= alpha;
            m_run = m_new;
        }

        float p[16];
#pragma unroll
        for (int sh = 0; sh < 4; ++sh)
#pragma unroll
            for (int r = 0; r < 4; ++r)
                p[sh * 4 + r] = __builtin_amdgcn_exp2f(scp[sh][r] - m_run);
        float s01 = (p[0] + p[1]) + (p[2] + p[3]);
        float s23 = (p[4] + p[5]) + (p[6] + p[7]);
        float s45 = (p[8] + p[9]) + (p[10] + p[11]);
        float s67 = (p[12] + p[13]) + (p[14] + p[15]);
        l_run += (s01 + s23) + (s45 + s67);

        union PU { u32x4 u; frag8 f; } p0u, p1u;
        p0u.u = (u32x4){cvtpk(p[0], p[1]),  cvtpk(p[2], p[3]),
                        cvtpk(p[4], p[5]),  cvtpk(p[6], p[7])};
        p1u.u = (u32x4){cvtpk(p[8], p[9]),  cvtpk(p[10], p[11]),
                        cvtpk(p[12], p[13]), cvtpk(p[14], p[15])};

        __builtin_amdgcn_s_setprio(1);
#pragma unroll
        for (int g = 0; g < 4; ++g) {
            bf4 v0 = *(const bf4*)(vrp0 + vbo + g * 2048);
            bf4 v1 = *(const bf4*)(vrp1 + vbo + g * 2048);
            bf4 v2 = *(const bf4*)(vrp2 + vbo + g * 2048);
            bf4 v3 = *(const bf4*)(vrp3 + vbo + g * 2048);
            frag8 vf0 = __builtin_shufflevector(v0, v1, 0, 1, 2, 3, 4, 5, 6, 7);
            frag8 vf1 = __builtin_shufflevector(v2, v3, 0, 1, 2, 3, 4, 5, 6, 7);
            o[g] = __builtin_amdgcn_mfma_f32_16x16x32_bf16(p0u.f, vf0, o[g], 0, 0, 0);
            o[g] = __builtin_amdgcn_mfma_f32_16x16x32_bf16(p1u.f, vf1, o[g], 0, 0, 0);
        }
        __builtin_amdgcn_s_setprio(0);
        vbo ^= 8192;
    };

    // QK^T of current K buffer; mask regs enter as MFMA C-init; result -> scp
    auto QKSAVE = [&]() {
        scp[0] = mA0; scp[1] = mA1; scp[2] = mA2; scp[3] = mA3;
        __builtin_amdgcn_s_setprio(1);
#pragma unroll
        for (int sh = 0; sh < 4; ++sh) {
            frag8 k0 = *(const frag8*)(krp0 + kbo + sh * 2048);
            frag8 k1 = *(const frag8*)(krp1 + kbo + sh * 2048);
            scp[sh] = __builtin_amdgcn_mfma_f32_16x16x32_bf16(k0, qf[0], scp[sh], 0, 0, 0);
            scp[sh] = __builtin_amdgcn_mfma_f32_16x16x32_bf16(k1, qf[1], scp[sh], 0, 0, 0);
        }
        __builtin_amdgcn_s_setprio(0);
        kbo ^= 8192;
    };

    // ---- iteration 0 (peeled) ----
    STAGE2();                      // tile 0 -> buf 0
    LOADM();                       // mask tile 0 -> mA
    vmwait<0>();
    __builtin_amdgcn_s_barrier();
    __builtin_amdgcn_sched_barrier(0);
    STAGE2();                      // tile 1 -> buf 1
    QKSAVE();                      // tile 0 (consumes mA)
    LOADM();                       // mask tile 1 -> mA

    // ---- steady state ----
    for (int i = 1; i < 16; ++i) {
        SOFTPV();                  // tile i-1 (V valid until STAGE below)
        vmwait<0>();
        __builtin_amdgcn_s_barrier();          // buf(i) ready; all done with buf^1
        __builtin_amdgcn_sched_barrier(0);
        if (i < 15) STAGE2();                  // tile i+1
        QKSAVE();                              // tile i (consumes mA)
        if (i < 15) LOADM();                   // mask tile i+1 -> mA
    }
    // ---- epilogue: tile 15 ----
    SOFTPV();
#undef STAGE2
#undef LOADM

    // deferred cross-lane l reduce (once)
    {
        float lA_ = __shfl_xor(l_run, 16);
        float lB_ = __shfl_xor(l_run, 32);
        float lC_ = __shfl_xor(l_run, 48);
        l_run = (l_run + lA_) + (lB_ + lC_);
    }

    // ---- merge group 1 partials into group 0, write out ----
    __syncthreads();
    float* oX = (float*)smem;                       // [64][68] padded f32
    float* mX = (float*)(smem + 64 * 68 * 4);       // [64]
    float* lX = mX + 64;

    if (grp == 1) {
#pragma unroll
        for (int g = 0; g < 4; ++g)
#pragma unroll
            for (int j = 0; j < 4; ++j)
                oX[(wq * 16 + 4 * hi + j) * 68 + g * 16 + ln] = o[g][j];
        if (hi == 0) { mX[wq * 16 + ln] = m_run; lX[wq * 16 + ln] = l_run; }
    }
    __syncthreads();
    if (grp == 0) {
#pragma unroll
        for (int j = 0; j < 4; ++j) {
            int q = 4 * hi + j;
            float mA = __shfl(m_run, q);
            float lA = __shfl(l_run, q);
            float mB = mX[wq * 16 + q];
            float lB = lX[wq * 16 + q];
            float mm = fmaxf(mA, mB);
            float aA = __builtin_amdgcn_exp2f(mA - mm);
            float aB = __builtin_amdgcn_exp2f(mB - mm);
            float inv = 1.0f / (lA * aA + lB * aB);
            aA *= inv; aB *= inv;
#pragma unroll
            for (int g = 0; g < 4; ++g) {
                float v = o[g][j] * aA + oX[(wq * 16 + q) * 68 + g * 16 + ln] * aB;
                long idx = ((long)b * L_ + q0 + q) * D_ + h * DH_ + g * 16 + ln;
                Og[idx] = f2bf(v);
            }
        }
    }
}

// ---------------- launch ----------------
extern "C" void kernel_launch(void* const* d_in, const int* in_sizes, int n_in,
                              void* d_out, int out_size, void* d_ws, size_t ws_size,
                              hipStream_t stream)
{
    const float* qx = (const float*)d_in[0];
    const float* kx = (const float*)d_in[1];
    const float* vx = (const float*)d_in[2];
    const float* ec = (const float*)d_in[3];
    const float* Wq = (const float*)d_in[4];
    const float* bq = (const float*)d_in[5];
    const float* Wk = (const float*)d_in[6];
    const float* bk = (const float*)d_in[7];
    const float* Wv = (const float*)d_in[8];
    const float* bv = (const float*)d_in[9];
    const float* Wo = (const float*)d_in[10];
    const float* bo = (const float*)d_in[11];
    float* out = (float*)d_out;

    const long NA = (long)B_ * L_ * D_;
    const long NW = (long)D_ * D_;

    unsigned short* Ap  = (unsigned short*)d_ws;   // attn output (bf16)
    unsigned short* wqb = Ap + NA;
    unsigned short* wkb = wqb + NW;
    unsigned short* wvb = wkb + NW;
    unsigned short* wob = wvb + NW;
    unsigned short* Qp  = wob + NW;
    unsigned short* Kp  = Qp + NA;
    unsigned short* Vtp = Kp + NA;       // V^T: [D][B*L], slot-swizzled
    float*          mk  = (float*)(Vtp + NA);

    const long nblk = (NW + B_ * L_ + 255) / 256;
    cvt_mask_kernel<<<dim3((unsigned)nblk), dim3(256), 0, stream>>>(
        Wq, Wk, Wv, Wo, ec, wqb, wkb, wvb, wob, mk);

    // fused QKV projections, A read directly as f32 (1536 blocks):
    // Q scaled, K plain, V transposed+swizzled
    GemmArgs zq = {qx, wqb, bq, Qp, 1};
    GemmArgs zk = {kx, wkb, bk, Kp, 0};
    GemmArgs zv = {vx, wvb, bv, Vtp, 2};
    gemm_kernel<64, 64, 1><<<dim3(8, 64, 3), dim3(256), 0, stream>>>(zq, zk, zv, B_ * L_, D_, D_);

    attn_kernel<<<dim3(L_ / 64, B_ * H_), dim3(512), 0, stream>>>(Qp, Kp, Vtp, mk, Ap);

    // output projection, bf16 A, f32 out (1024 blocks)
    GemmArgs zo = {Ap, wob, bo, out, 3};
    gemm_kernel<32, 64, 0><<<dim3(8, 128, 1), dim3(256), 0, stream>>>(zo, zo, zo, B_ * L_, D_, D_);
}